// Round 13
// baseline (69.195 us; speedup 1.0000x reference)
//
#include <hip/hip_runtime.h>

#define M_PAD 512

typedef float f32x4 __attribute__((ext_vector_type(4)));

// Seeded wave-parallel lower_bound over sorted ri[0..T): first idx with
// ri[idx] >= target. Seed: expected position target*T/N, window +-4096
// (boundary counts are multinomial, sigma ~1K, so one window almost always
// brackets; x8 gallop expansion keeps it provably correct).
// Then 65-ary wave rounds: 8192 -> ~126 -> ~2 -> 64-probe finish.
__device__ __forceinline__ int lower_bound_seeded(const int* __restrict__ ri,
                                                  int T, int N, int target,
                                                  int lane) {
    int guess = (int)(((long long)target * T) / N);
    int W = 4096;
    int lo = max(0, guess - W), hi = min(T, guess + W);
    // Verify bracket: LB >= lo iff (lo==0 || ri[lo-1] < target);
    //                 LB <= hi iff (hi==T || ri[hi] >= target).
    while (true) {
        bool okLo = (lo == 0) || (ri[lo - 1] < target);   // uniform addr -> broadcast
        bool okHi = (hi == T) || (ri[hi] >= target);
        if (okLo && okHi) break;
        W <<= 3;
        lo = max(0, guess - W); hi = min(T, guess + W);    // <=5 expansions covers T
    }
    while (hi - lo > 64) {
        int len = hi - lo;
        int probe = lo + (len * (lane + 1)) / 65;          // strictly inside (lo,hi)
        int v = ri[probe];
        unsigned long long m = __ballot(v < target);        // prefix mask (sorted)
        int k = __popcll(m);
        int nlo = (k == 0)  ? lo : lo + (len * k) / 65;
        int nhi = (k == 64) ? hi : lo + (len * (k + 1)) / 65;
        lo = nlo; hi = nhi;
    }
    int p = lo + lane;
    int v = (p < hi) ? ri[p] : 2147483647;                  // sentinel
    unsigned long long m = __ballot(v < target);
    return lo + __popcll(m);
}

// Single dispatch. Block (1024 thr) covers TWO rays r0=2*bid, r0+1.
// Waves 0..2 search LB(r0), LB(r0+1), LB(r0+2) in parallel (3 searches per
// 2 rays vs 4 per ray before). Body identical to the 69us R12 kernel:
// one slot/thread, dense lane-consecutive gather i=s+j, nt stores.
__global__ __launch_bounds__(1024)
void mono_kernel(const float* __restrict__ rays,
                 const int* __restrict__ ri,
                 const float* __restrict__ ts,
                 const float* __restrict__ te,
                 float* __restrict__ xyz_out,     // (T,4)
                 float* __restrict__ ray_valid,   // (N,512)
                 float* __restrict__ z_vals,      // (N,512)
                 float* __restrict__ dists,       // (N,512)
                 float* __restrict__ xyz_w,       // (N,512,4)
                 float* __restrict__ whole_valid, // (N,)
                 int N, int T) {
    const int r0 = blockIdx.x * 2;
    const int tid = threadIdx.x;
    const int wave = tid >> 6, lane = tid & 63;

    __shared__ int sh[3];
    if (wave < 3) {
        int lb = lower_bound_seeded(ri, T, N, r0 + wave, lane);
        if (lane == 0) sh[wave] = lb;
    }
    __syncthreads();

    const int k = tid >> 9;              // local ray 0/1
    const int j = tid & (M_PAD - 1);
    const int r = r0 + k;
    const int s = sh[k];
    const int cnt = sh[k + 1] - s;
    const int idx = (r << 9) + j;

    float z = 0.0f, dd = 0.0f, v = 0.0f;
    f32x4 pt = {0.f, 0.f, 0.f, 0.f};

    if (j < cnt) {
        int i = s + j;
        float a = ts[i], bb = te[i];          // dense: lane-consecutive i
        z  = (a + bb) * 0.5f;
        dd = bb - a;
        v  = 1.0f;
        const float* rc = rays + (size_t)r * 6;   // wave-uniform -> broadcast
        pt.x = fmaf(z, rc[3], rc[0]);
        pt.y = fmaf(z, rc[4], rc[1]);
        pt.z = fmaf(z, rc[5], rc[2]);
        __builtin_nontemporal_store(pt, reinterpret_cast<f32x4*>(xyz_out) + i);
    }

    __builtin_nontemporal_store(z,  &z_vals[idx]);
    __builtin_nontemporal_store(dd, &dists[idx]);
    __builtin_nontemporal_store(v,  &ray_valid[idx]);
    __builtin_nontemporal_store(pt, reinterpret_cast<f32x4*>(xyz_w) + idx);

    if (j == 0) whole_valid[r] = 1.0f;
}

extern "C" void kernel_launch(void* const* d_in, const int* in_sizes, int n_in,
                              void* d_out, int out_size, void* d_ws, size_t ws_size,
                              hipStream_t stream) {
    const float* rays = (const float*)d_in[0];  // (N,6)
    const int*   ri   = (const int*)d_in[1];    // (T,) sorted
    const float* ts   = (const float*)d_in[2];  // (T,)
    const float* te   = (const float*)d_in[3];  // (T,)
    const int N = in_sizes[0] / 6;
    const int T = in_sizes[1];

    float* out         = (float*)d_out;
    float* xyz_out     = out;                                    // T*4
    float* ray_valid   = xyz_out + (size_t)T * 4;                // N*512
    float* z_vals      = ray_valid + (size_t)N * M_PAD;          // N*512
    float* dists       = z_vals + (size_t)N * M_PAD;             // N*512
    float* whole_valid = dists + (size_t)N * M_PAD;              // N
    float* xyz_w       = whole_valid + N;                        // N*512*4

    mono_kernel<<<N / 2, 1024, 0, stream>>>(rays, ri, ts, te,
                                            xyz_out, ray_valid, z_vals,
                                            dists, xyz_w, whole_valid, N, T);
}